// Round 5
// baseline (200.378 us; speedup 1.0000x reference)
//
#include <hip/hip_runtime.h>
#include <cstdint>
#include <cstddef>

// Problem constants (AltAttention: B=2, S=2048, D=1024, H=16, dh=64)
#define B_  2
#define S_  2048
#define D_  1024
#define H_  16
#define DH_ 64
#define M_  (B_*S_)     // 4096 rows
#define N3_ (3*D_)      // 3072 qkv cols
#define NT_ (S_/64)     // 32 key tiles

typedef float f32x4 __attribute__((ext_vector_type(4)));
typedef short short8 __attribute__((ext_vector_type(8)));
typedef unsigned short u16x8 __attribute__((ext_vector_type(8)));
typedef unsigned short u16x4 __attribute__((ext_vector_type(4)));

__device__ __forceinline__ unsigned short f2bf(float x) {
    unsigned int u = __float_as_uint(x);
    unsigned int r = (u + 0x7FFFu + ((u >> 16) & 1u)) >> 16;
    return (unsigned short)r;
}

__device__ __forceinline__ float exp2_(float x) { return __builtin_amdgcn_exp2f(x); }

__device__ __forceinline__ unsigned int cvt_pk_bf16(float a, float b) {
    unsigned int r;
    asm volatile("v_cvt_pk_bf16_f32 %0, %1, %2" : "=v"(r) : "v"(a), "v"(b));
    return r;
}

__device__ __forceinline__ void gload16(const void* g, void* l) {
    __builtin_amdgcn_global_load_lds(
        (const __attribute__((address_space(1))) unsigned int*)g,
        (__attribute__((address_space(3))) unsigned int*)l,
        16, 0, 0);
}

// ---------------------------------------------------------------------------
// Mask layout detection (verified rounds 1-4)
// ---------------------------------------------------------------------------
__global__ void k_detect_mask(const unsigned char* __restrict__ mb, int* __restrict__ flag) {
    __shared__ int sBig, sM4, sM8;
    if (threadIdx.x == 0) { sBig = 0; sM4 = 0; sM8 = 0; }
    __syncthreads();
    int big = 0, m4 = 0, m8 = 0;
    for (int i = threadIdx.x; i < 4096; i += blockDim.x) {
        unsigned char v = mb[i];
        if (v > 1) big = 1;
        if (v && (i & 3)) m4 = 1;
        if (v && ((i & 7) == 4)) m8 = 1;
    }
    if (big) atomicOr(&sBig, 1);
    if (m4)  atomicOr(&sM4, 1);
    if (m8)  atomicOr(&sM8, 1);
    __syncthreads();
    if (threadIdx.x == 0) {
        int w;
        if (sBig)      w = 0;
        else if (sM4)  w = 1;
        else if (sM8)  w = 4;
        else           w = 8;
        *flag = w;
    }
}

// One wave per 64-key tile -> uint64 bitmask via ballot.
__global__ void k_maskbits(const void* __restrict__ mask, const int* __restrict__ flag,
                           unsigned long long* __restrict__ bits) {
    int i = blockIdx.x * 64 + threadIdx.x;
    int w = *flag;
    bool on;
    if (w == 0)      on = ((const float*)mask)[i] != 0.0f;
    else if (w == 1) on = ((const unsigned char*)mask)[i] != 0;
    else if (w == 4) on = ((const int*)mask)[i] != 0;
    else             on = ((const long long*)mask)[i] != 0;
    unsigned long long bal = __ballot(on);
    if (threadIdx.x == 0) bits[blockIdx.x] = bal;
}

// ---------------------------------------------------------------------------
// fp32 -> bf16 convert (vectorized)
// ---------------------------------------------------------------------------
__global__ void k_f2bf(const float* __restrict__ in, unsigned short* __restrict__ out, int n) {
    int i = (blockIdx.x * blockDim.x + threadIdx.x) * 4;
    if (i >= n) return;
    float4 v = *reinterpret_cast<const float4*>(&in[i]);
    u16x4 o = { f2bf(v.x), f2bf(v.y), f2bf(v.z), f2bf(v.w) };
    *reinterpret_cast<u16x4*>(&out[i]) = o;
}

// ---------------------------------------------------------------------------
// bf16 MFMA GEMM (m97 structure, verified round 3)
// ---------------------------------------------------------------------------
template <bool OUT_BF16>
__global__ __launch_bounds__(256) void k_gemm_bf16_nt(
    const unsigned short* __restrict__ A, const unsigned short* __restrict__ W,
    const float* __restrict__ bias, void* __restrict__ Cout,
    int M, int N, int K) {
    __shared__ __align__(16) unsigned short Al[128 * 64];
    __shared__ __align__(16) unsigned short Wl[128 * 64];

    const int tid  = threadIdx.x;
    const int lane = tid & 63;
    const int w    = tid >> 6;
    const int wr   = w >> 1, wc = w & 1;
    const int l16  = lane & 15, g = lane >> 4;
    const int m0 = blockIdx.y * 128, n0 = blockIdx.x * 128;

    f32x4 acc[4][4];
#pragma unroll
    for (int m = 0; m < 4; ++m)
#pragma unroll
        for (int n = 0; n < 4; ++n) acc[m][n] = (f32x4){0.f, 0.f, 0.f, 0.f};

    const int srow = tid >> 3, scol = (tid & 7) * 8;

    for (int k0 = 0; k0 < K; k0 += 64) {
        __syncthreads();
#pragma unroll
        for (int i = 0; i < 4; ++i) {
            const int c = i * 256 + tid;
            const int row = srow + i * 32;
            gload16(A + (size_t)(m0 + row) * K + k0 + scol, Al + c * 8);
            gload16(W + (size_t)(n0 + row) * K + k0 + scol, Wl + c * 8);
        }
        __syncthreads();

#pragma unroll
        for (int kk = 0; kk < 2; ++kk) {
            short8 a[4], b[4];
#pragma unroll
            for (int m = 0; m < 4; ++m)
                a[m] = *reinterpret_cast<const short8*>(
                    &Al[(size_t)(wr * 64 + m * 16 + l16) * 64 + kk * 32 + g * 8]);
#pragma unroll
            for (int n = 0; n < 4; ++n)
                b[n] = *reinterpret_cast<const short8*>(
                    &Wl[(size_t)(wc * 64 + n * 16 + l16) * 64 + kk * 32 + g * 8]);
#pragma unroll
            for (int m = 0; m < 4; ++m)
#pragma unroll
                for (int n = 0; n < 4; ++n)
                    acc[m][n] = __builtin_amdgcn_mfma_f32_16x16x32_bf16(a[m], b[n], acc[m][n], 0, 0, 0);
        }
    }

    float bv[4];
#pragma unroll
    for (int n = 0; n < 4; ++n) bv[n] = bias[n0 + wc * 64 + n * 16 + l16];
#pragma unroll
    for (int m = 0; m < 4; ++m) {
#pragma unroll
        for (int r = 0; r < 4; ++r) {
            const size_t row = m0 + wr * 64 + m * 16 + g * 4 + r;
#pragma unroll
            for (int n = 0; n < 4; ++n) {
                const int col = n0 + wc * 64 + n * 16 + l16;
                float v = acc[m][n][r] + bv[n];
                if (OUT_BF16)
                    ((unsigned short*)Cout)[row * N + col] = f2bf(v);
                else
                    ((float*)Cout)[row * N + col] = v;
            }
        }
    }
}

// ---------------------------------------------------------------------------
// Flash attention, swapped-QK^T softmax, bf16 MFMA.
// Round-5 changes: additive mask Am[2048] in LDS (computed once per block),
// mask applied pre-max inside score addend (kills post-exp select pass);
// s_setprio(1) around MFMA clusters; l-update deferred past PV issue.
// ---------------------------------------------------------------------------
__global__ __launch_bounds__(256) void k_attn_mfma(
    const unsigned short* __restrict__ qkv,
    const unsigned long long* __restrict__ mbits,
    unsigned short* __restrict__ x) {
    __shared__ __align__(16) unsigned short Kt[64][72];
    __shared__ __align__(16) unsigned short Vt[64][72];
    __shared__ __align__(16) unsigned short QP[64][72];
    __shared__ __align__(16) float Am[S_];

    const int tid  = threadIdx.x;
    const int lane = tid & 63;
    const int wq   = tid >> 6;
    const int g    = lane >> 4;
    const int g4   = g * 4;
    const int l16  = lane & 15;

    const int nqt = S_ / 64;
    const int qt = blockIdx.x % nqt;
    const int h  = (blockIdx.x / nqt) % H_;
    const int b  = blockIdx.x / (nqt * H_);
    const int q0 = qt * 64;
    const size_t rowbase = (size_t)b * S_ * N3_;
    const int hq = h * 192, hk = hq + 64, hv = hq + 128;
    const unsigned short* kvb = qkv + rowbase;

    // ---- additive mask array (once per block): Am[k] = on ? 0 : -1e30
    {
#pragma unroll
        for (int it = 0; it < S_ / 256; ++it) {
            const int k = it * 256 + tid;
            const unsigned long long w = mbits[b * NT_ + (k >> 6)];
            Am[k] = ((w >> (k & 63)) & 1ull) ? 0.0f : -1e30f;
        }
    }

    // ---- stage Q tile (64 x 64)
    {
        const int row = tid >> 2, cb = (tid & 3) * 16;
        const unsigned short* src = kvb + (size_t)(q0 + row) * N3_ + hq + cb;
        *reinterpret_cast<u16x8*>(&QP[row][cb])     = *reinterpret_cast<const u16x8*>(src);
        *reinterpret_cast<u16x8*>(&QP[row][cb + 8]) = *reinterpret_cast<const u16x8*>(src + 8);
    }
    __syncthreads();

    const short8 qa0 = *reinterpret_cast<const short8*>(&QP[wq*16 + l16][g*8]);
    const short8 qa1 = *reinterpret_cast<const short8*>(&QP[wq*16 + l16][32 + g*8]);

    f32x4 Oacc[4];
#pragma unroll
    for (int df = 0; df < 4; ++df) Oacc[df] = (f32x4){0.f, 0.f, 0.f, 0.f};
    float m = -1e30f, l = 0.0f;

    const float LOG2E = 1.4426950408889634f;
    const float c1 = 0.03125f * LOG2E;                       // scale * log2e
    const float c2 = exp2f(-0.5f * (float)(h + 1)) * LOG2E;  // slope * log2e
    const int   qg = q0 + wq * 16 + l16;                     // this lane's q row
    float albr[4];
#pragma unroll
    for (int r = 0; r < 4; ++r) albr[r] = c2 * (float)(g4 + r);
    const float c2_16 = c2 * 16.0f;

    // staging geometry
    const int krow = tid >> 2, kcb = (tid & 3) * 16;
    const int vkb = (tid & 15) * 4, vdb = (tid >> 4) * 4;
    u16x8 kr0, kr1;
    u16x4 vr0, vr1, vr2, vr3;

    // preload tile 0
    {
        const unsigned short* ks = kvb + (size_t)krow * N3_ + hk + kcb;
        kr0 = *reinterpret_cast<const u16x8*>(ks);
        kr1 = *reinterpret_cast<const u16x8*>(ks + 8);
        const unsigned short* vs = kvb + (size_t)vkb * N3_ + hv + vdb;
        vr0 = *reinterpret_cast<const u16x4*>(vs);
        vr1 = *reinterpret_cast<const u16x4*>(vs + N3_);
        vr2 = *reinterpret_cast<const u16x4*>(vs + 2 * N3_);
        vr3 = *reinterpret_cast<const u16x4*>(vs + 3 * N3_);
    }

    for (int t = 0; t < NT_; ++t) {
        const int k0 = t * 64;
        __syncthreads();   // prior tile's LDS reads done

        // ---- write staged regs to LDS
        *reinterpret_cast<u16x8*>(&Kt[krow][kcb])     = kr0;
        *reinterpret_cast<u16x8*>(&Kt[krow][kcb + 8]) = kr1;
        {
            u16x4 w0 = { vr0.x, vr1.x, vr2.x, vr3.x };
            u16x4 w1 = { vr0.y, vr1.y, vr2.y, vr3.y };
            u16x4 w2 = { vr0.z, vr1.z, vr2.z, vr3.z };
            u16x4 w3 = { vr0.w, vr1.w, vr2.w, vr3.w };
            *reinterpret_cast<u16x4*>(&Vt[vdb + 0][vkb]) = w0;
            *reinterpret_cast<u16x4*>(&Vt[vdb + 1][vkb]) = w1;
            *reinterpret_cast<u16x4*>(&Vt[vdb + 2][vkb]) = w2;
            *reinterpret_cast<u16x4*>(&Vt[vdb + 3][vkb]) = w3;
        }
        // ---- issue next tile's loads (in flight during compute)
        if (t + 1 < NT_) {
            const int kn = k0 + 64;
            const unsigned short* ks = kvb + (size_t)(kn + krow) * N3_ + hk + kcb;
            kr0 = *reinterpret_cast<const u16x8*>(ks);
            kr1 = *reinterpret_cast<const u16x8*>(ks + 8);
            const unsigned short* vs = kvb + (size_t)(kn + vkb) * N3_ + hv + vdb;
            vr0 = *reinterpret_cast<const u16x4*>(vs);
            vr1 = *reinterpret_cast<const u16x4*>(vs + N3_);
            vr2 = *reinterpret_cast<const u16x4*>(vs + 2 * N3_);
            vr3 = *reinterpret_cast<const u16x4*>(vs + 3 * N3_);
        }
        __syncthreads();

        // ---- swapped QK^T: lane holds 16 scores for q=l16, key=jb*16+g4+r
        float p_[4][4];
        __builtin_amdgcn_s_setprio(1);
#pragma unroll
        for (int jb = 0; jb < 4; ++jb) {
            short8 kb0 = *reinterpret_cast<const short8*>(&Kt[jb*16 + l16][g*8]);
            short8 kb1 = *reinterpret_cast<const short8*>(&Kt[jb*16 + l16][32 + g*8]);
            f32x4 c = (f32x4){0.f, 0.f, 0.f, 0.f};
            c = __builtin_amdgcn_mfma_f32_16x16x32_bf16(kb0, qa0, c, 0, 0, 0);
            c = __builtin_amdgcn_mfma_f32_16x16x32_bf16(kb1, qa1, c, 0, 0, 0);
#pragma unroll
            for (int r = 0; r < 4; ++r) p_[jb][r] = c[r];
        }
        __builtin_amdgcn_s_setprio(0);

        // ---- additive mask values for this tile (broadcast ds_read)
        f32x4 amv[4];
#pragma unroll
        for (int jb = 0; jb < 4; ++jb)
            amv[jb] = *reinterpret_cast<const f32x4*>(&Am[k0 + jb * 16 + g4]);

        // ---- scores in log2 domain, alibi + mask folded into fma addend
        if (k0 < q0) {            // all keys < q-tile
            const float tb = c2 * (float)(k0 - qg);
#pragma unroll
            for (int jb = 0; jb < 4; ++jb) {
                const float tbj = tb + c2_16 * (float)jb;
#pragma unroll
                for (int r = 0; r < 4; ++r)
                    p_[jb][r] = fmaf(p_[jb][r], c1, tbj + albr[r] + amv[jb][r]);
            }
        } else if (k0 > q0) {     // all keys > q-tile
            const float tb = c2 * (float)(k0 - qg);
#pragma unroll
            for (int jb = 0; jb < 4; ++jb) {
                const float tbj = -tb - c2_16 * (float)jb;
#pragma unroll
                for (int r = 0; r < 4; ++r)
                    p_[jb][r] = fmaf(p_[jb][r], c1, tbj - albr[r] + amv[jb][r]);
            }
        } else {                  // diagonal tile
            const int dbase = k0 - qg;
#pragma unroll
            for (int jb = 0; jb < 4; ++jb)
#pragma unroll
                for (int r = 0; r < 4; ++r) {
                    int d = dbase + jb * 16 + g4 + r;
                    d = d < 0 ? -d : d;
                    p_[jb][r] = fmaf(p_[jb][r], c1, amv[jb][r] - c2 * (float)d);
                }
        }

        // ---- row max (masked scores are -1e30: excluded naturally)
        float mx;
        {
            float m0_ = fmaxf(fmaxf(p_[0][0], p_[0][1]), fmaxf(p_[0][2], p_[0][3]));
            float m1_ = fmaxf(fmaxf(p_[1][0], p_[1][1]), fmaxf(p_[1][2], p_[1][3]));
            float m2_ = fmaxf(fmaxf(p_[2][0], p_[2][1]), fmaxf(p_[2][2], p_[2][3]));
            float m3_ = fmaxf(fmaxf(p_[3][0], p_[3][1]), fmaxf(p_[3][2], p_[3][3]));
            mx = fmaxf(fmaxf(m0_, m1_), fmaxf(m2_, m3_));
        }
        mx = fmaxf(mx, __shfl_xor(mx, 16));
        mx = fmaxf(mx, __shfl_xor(mx, 32));

        // ---- defer-max rescale (rare)
        if (__any(mx > m + 8.0f)) {
            const float mn = fmaxf(m, mx);
            const float cr = exp2_(m - mn);
            m = mn;
            l *= cr;
            const int srcb = (lane & 48) + ((lane & 48) >> 2);
#pragma unroll
            for (int r = 0; r < 4; ++r) {
                const float crq = __shfl(cr, srcb + r);
#pragma unroll
                for (int df = 0; df < 4; ++df) Oacc[df][r] *= crq;
            }
        }

        // ---- exp + local sum (masked -> exp2(-huge) = 0)
        float ps = 0.0f;
#pragma unroll
        for (int jb = 0; jb < 4; ++jb)
#pragma unroll
            for (int r = 0; r < 4; ++r) {
                float p = exp2_(p_[jb][r] - m);
                p_[jb][r] = p;
                ps += p;
            }

        // ---- pack P to bf16, write to per-wave LDS strip (same-wave read)
#pragma unroll
        for (int jb = 0; jb < 4; ++jb) {
            uint2 st;
            st.x = cvt_pk_bf16(p_[jb][0], p_[jb][1]);
            st.y = cvt_pk_bf16(p_[jb][2], p_[jb][3]);
            *reinterpret_cast<uint2*>(&QP[wq*16 + l16][jb*16 + g4]) = st;
        }

        // ---- PV: A = P, B = Vt
        const short8 pa0 = *reinterpret_cast<const short8*>(&QP[wq*16 + l16][g*8]);
        const short8 pa1 = *reinterpret_cast<const short8*>(&QP[wq*16 + l16][32 + g*8]);
        __builtin_amdgcn_s_setprio(1);
#pragma unroll
        for (int df = 0; df < 4; ++df) {
            short8 vb0 = *reinterpret_cast<const short8*>(&Vt[df*16 + l16][g*8]);
            short8 vb1 = *reinterpret_cast<const short8*>(&Vt[df*16 + l16][32 + g*8]);
            Oacc[df] = __builtin_amdgcn_mfma_f32_16x16x32_bf16(pa0, vb0, Oacc[df], 0, 0, 0);
            Oacc[df] = __builtin_amdgcn_mfma_f32_16x16x32_bf16(pa1, vb1, Oacc[df], 0, 0, 0);
        }
        __builtin_amdgcn_s_setprio(0);

        // ---- l update (deferred past PV issue)
        ps += __shfl_xor(ps, 16);
        ps += __shfl_xor(ps, 32);
        l += ps;
    }

    // ---- normalize (l lives at lane l16=q; broadcast to output rows) + store
    const int srcb = (lane & 48) + ((lane & 48) >> 2);
    float invq[4];
#pragma unroll
    for (int r = 0; r < 4; ++r) invq[r] = 1.0f / __shfl(l, srcb + r);
#pragma unroll
    for (int df = 0; df < 4; ++df) {
#pragma unroll
        for (int r = 0; r < 4; ++r) {
            const int qrow = q0 + wq * 16 + g4 + r;
            x[(size_t)(b * S_ + qrow) * D_ + h * 64 + df * 16 + l16] = f2bf(Oacc[df][r] * invq[r]);
        }
    }
}

// ---------------------------------------------------------------------------
extern "C" void kernel_launch(void* const* d_in, const int* in_sizes, int n_in,
                              void* d_out, int out_size, void* d_ws, size_t ws_size,
                              hipStream_t stream) {
    const float* inputs = (const float*)d_in[0];
    const void*  mask   = d_in[1];
    const float* Wqkv   = (const float*)d_in[2];
    const float* bqkv   = (const float*)d_in[3];
    const float* Wproj  = (const float*)d_in[4];
    const float* bproj  = (const float*)d_in[5];
    float* out = (float*)d_out;

    // workspace layout
    unsigned short* qkvb = (unsigned short*)d_ws;         // M*N3 bf16
    unsigned short* xb   = qkvb + (size_t)M_ * N3_;       // M*D  bf16
    unsigned short* Ab   = xb + (size_t)M_ * D_;          // M*D  bf16 (inputs)
    unsigned short* Wqb  = Ab + (size_t)M_ * D_;          // N3*D bf16
    unsigned short* Wpb  = Wqb + (size_t)N3_ * D_;        // D*D  bf16
    unsigned long long* bits = (unsigned long long*)(Wpb + (size_t)D_ * D_);  // B*NT u64
    int* flag = (int*)(bits + B_ * NT_);

    k_detect_mask<<<1, 256, 0, stream>>>((const unsigned char*)mask, flag);
    k_maskbits<<<B_ * NT_, 64, 0, stream>>>(mask, flag, bits);

    k_f2bf<<<(M_ * D_ / 4 + 255) / 256, 256, 0, stream>>>(inputs, Ab, M_ * D_);
    k_f2bf<<<(N3_ * D_ / 4 + 255) / 256, 256, 0, stream>>>(Wqkv, Wqb, N3_ * D_);
    k_f2bf<<<(D_ * D_ / 4 + 255) / 256, 256, 0, stream>>>(Wproj, Wpb, D_ * D_);

    dim3 g1(N3_ / 128, M_ / 128);   // 24 x 32
    k_gemm_bf16_nt<true><<<g1, 256, 0, stream>>>(Ab, Wqb, bqkv, qkvb, M_, N3_, D_);

    k_attn_mfma<<<B_ * H_ * (S_ / 64), 256, 0, stream>>>(qkvb, bits, xb);

    dim3 g2(D_ / 128, M_ / 128);    // 8 x 32
    k_gemm_bf16_nt<false><<<g2, 256, 0, stream>>>(xb, Wpb, bproj, out, M_, D_, D_);
}

// Round 6
// 178.189 us; speedup vs baseline: 1.1245x; 1.1245x over previous
//
#include <hip/hip_runtime.h>
#include <cstdint>
#include <cstddef>

// Problem constants (AltAttention: B=2, S=2048, D=1024, H=16, dh=64)
#define B_  2
#define S_  2048
#define D_  1024
#define H_  16
#define DH_ 64
#define M_  (B_*S_)     // 4096 rows
#define N3_ (3*D_)      // 3072 qkv cols
#define NT_ (S_/64)     // 32 key tiles

typedef float f32x4 __attribute__((ext_vector_type(4)));
typedef short short8 __attribute__((ext_vector_type(8)));
typedef unsigned short u16x8 __attribute__((ext_vector_type(8)));
typedef unsigned short u16x4 __attribute__((ext_vector_type(4)));
typedef unsigned short u16x2 __attribute__((ext_vector_type(2)));

__device__ __forceinline__ unsigned short f2bf(float x) {
    unsigned int u = __float_as_uint(x);
    unsigned int r = (u + 0x7FFFu + ((u >> 16) & 1u)) >> 16;
    return (unsigned short)r;
}

__device__ __forceinline__ float exp2_(float x) { return __builtin_amdgcn_exp2f(x); }

__device__ __forceinline__ unsigned int cvt_pk_bf16(float a, float b) {
    unsigned int r;
    asm volatile("v_cvt_pk_bf16_f32 %0, %1, %2" : "=v"(r) : "v"(a), "v"(b));
    return r;
}

__device__ __forceinline__ void gload16(const void* g, void* l) {
    __builtin_amdgcn_global_load_lds(
        (const __attribute__((address_space(1))) unsigned int*)g,
        (__attribute__((address_space(3))) unsigned int*)l,
        16, 0, 0);
}

// ---------------------------------------------------------------------------
// Mask layout detection (verified rounds 1-5)
// ---------------------------------------------------------------------------
__global__ void k_detect_mask(const unsigned char* __restrict__ mb, int* __restrict__ flag) {
    __shared__ int sBig, sM4, sM8;
    if (threadIdx.x == 0) { sBig = 0; sM4 = 0; sM8 = 0; }
    __syncthreads();
    int big = 0, m4 = 0, m8 = 0;
    for (int i = threadIdx.x; i < 4096; i += blockDim.x) {
        unsigned char v = mb[i];
        if (v > 1) big = 1;
        if (v && (i & 3)) m4 = 1;
        if (v && ((i & 7) == 4)) m8 = 1;
    }
    if (big) atomicOr(&sBig, 1);
    if (m4)  atomicOr(&sM4, 1);
    if (m8)  atomicOr(&sM8, 1);
    __syncthreads();
    if (threadIdx.x == 0) {
        int w;
        if (sBig)      w = 0;
        else if (sM4)  w = 1;
        else if (sM8)  w = 4;
        else           w = 8;
        *flag = w;
    }
}

// Additive mask bias (round-1 proven): 0 or -1e30, fp32, L2-resident (16 KB).
__global__ void k_expand_mask(const void* __restrict__ mask, const int* __restrict__ flag,
                              float* __restrict__ maskbias, int n) {
    int i = blockIdx.x * blockDim.x + threadIdx.x;
    if (i >= n) return;
    int w = *flag;
    bool on;
    if (w == 0)      on = ((const float*)mask)[i] != 0.0f;
    else if (w == 1) on = ((const unsigned char*)mask)[i] != 0;
    else if (w == 4) on = ((const int*)mask)[i] != 0;
    else             on = ((const long long*)mask)[i] != 0;
    maskbias[i] = on ? 0.0f : -1e30f;
}

// ---------------------------------------------------------------------------
// fp32 -> bf16 convert (vectorized)
// ---------------------------------------------------------------------------
__global__ void k_f2bf(const float* __restrict__ in, unsigned short* __restrict__ out, int n) {
    int i = (blockIdx.x * blockDim.x + threadIdx.x) * 4;
    if (i >= n) return;
    float4 v = *reinterpret_cast<const float4*>(&in[i]);
    u16x4 o = { f2bf(v.x), f2bf(v.y), f2bf(v.z), f2bf(v.w) };
    *reinterpret_cast<u16x4*>(&out[i]) = o;
}

// ---------------------------------------------------------------------------
// bf16 MFMA GEMM (m97 structure, verified round 3)
// ---------------------------------------------------------------------------
template <bool OUT_BF16>
__global__ __launch_bounds__(256) void k_gemm_bf16_nt(
    const unsigned short* __restrict__ A, const unsigned short* __restrict__ W,
    const float* __restrict__ bias, void* __restrict__ Cout,
    int M, int N, int K) {
    __shared__ __align__(16) unsigned short Al[128 * 64];
    __shared__ __align__(16) unsigned short Wl[128 * 64];

    const int tid  = threadIdx.x;
    const int lane = tid & 63;
    const int w    = tid >> 6;
    const int wr   = w >> 1, wc = w & 1;
    const int l16  = lane & 15, g = lane >> 4;
    const int m0 = blockIdx.y * 128, n0 = blockIdx.x * 128;

    f32x4 acc[4][4];
#pragma unroll
    for (int m = 0; m < 4; ++m)
#pragma unroll
        for (int n = 0; n < 4; ++n) acc[m][n] = (f32x4){0.f, 0.f, 0.f, 0.f};

    const int srow = tid >> 3, scol = (tid & 7) * 8;

    for (int k0 = 0; k0 < K; k0 += 64) {
        __syncthreads();
#pragma unroll
        for (int i = 0; i < 4; ++i) {
            const int c = i * 256 + tid;
            const int row = srow + i * 32;
            gload16(A + (size_t)(m0 + row) * K + k0 + scol, Al + c * 8);
            gload16(W + (size_t)(n0 + row) * K + k0 + scol, Wl + c * 8);
        }
        __syncthreads();

#pragma unroll
        for (int kk = 0; kk < 2; ++kk) {
            short8 a[4], b[4];
#pragma unroll
            for (int m = 0; m < 4; ++m)
                a[m] = *reinterpret_cast<const short8*>(
                    &Al[(size_t)(wr * 64 + m * 16 + l16) * 64 + kk * 32 + g * 8]);
#pragma unroll
            for (int n = 0; n < 4; ++n)
                b[n] = *reinterpret_cast<const short8*>(
                    &Wl[(size_t)(wc * 64 + n * 16 + l16) * 64 + kk * 32 + g * 8]);
#pragma unroll
            for (int m = 0; m < 4; ++m)
#pragma unroll
                for (int n = 0; n < 4; ++n)
                    acc[m][n] = __builtin_amdgcn_mfma_f32_16x16x32_bf16(a[m], b[n], acc[m][n], 0, 0, 0);
        }
    }

    float bv[4];
#pragma unroll
    for (int n = 0; n < 4; ++n) bv[n] = bias[n0 + wc * 64 + n * 16 + l16];
#pragma unroll
    for (int m = 0; m < 4; ++m) {
#pragma unroll
        for (int r = 0; r < 4; ++r) {
            const size_t row = m0 + wr * 64 + m * 16 + g * 4 + r;
#pragma unroll
            for (int n = 0; n < 4; ++n) {
                const int col = n0 + wc * 64 + n * 16 + l16;
                float v = acc[m][n][r] + bv[n];
                if (OUT_BF16)
                    ((unsigned short*)Cout)[row * N + col] = f2bf(v);
                else
                    ((float*)Cout)[row * N + col] = v;
            }
        }
    }
}

// ---------------------------------------------------------------------------
// Flash attention, swapped-QK^T softmax, bf16 MFMA.
// Round-6 structure: 8 waves (512 thr), 128 q-rows/block; K/V LDS
// double-buffered -> ONE barrier per tile; next-tile loads issued at top
// of iter, LDS write at bottom (T14); mask = global fp32 bias folded into
// the score fma addend (no LDS cost, no post-exp pass).
// LDS = 2*9216(K) + 2*9216(V) + 18432(QP) = 55296 B -> 2 blocks/CU.
// ---------------------------------------------------------------------------
__global__ __launch_bounds__(512) void k_attn_mfma(
    const unsigned short* __restrict__ qkv,
    const float* __restrict__ maskbias,
    unsigned short* __restrict__ x) {
    __shared__ __align__(16) unsigned short Kt[2][64][72];
    __shared__ __align__(16) unsigned short Vt[2][64][72];
    __shared__ __align__(16) unsigned short QP[128][72];

    const int tid  = threadIdx.x;
    const int lane = tid & 63;
    const int wq   = tid >> 6;           // wave 0..7 -> 16-row q-strip
    const int g    = lane >> 4;
    const int g4   = g * 4;
    const int l16  = lane & 15;

    const int nqt = S_ / 128;            // 16 q-tiles
    const int qt = blockIdx.x % nqt;
    const int h  = (blockIdx.x / nqt) % H_;
    const int b  = blockIdx.x / (nqt * H_);
    const int q0 = qt * 128;
    const size_t rowbase = (size_t)b * S_ * N3_;
    const int hq = h * 192, hk = hq + 64, hv = hq + 128;
    const unsigned short* kvb = qkv + rowbase;
    const float* mbp = maskbias + b * S_;

    // ---- stage Q tile (128 x 64): each wave only reads its own 16 rows later
    {
        const int row = tid >> 2, cb = (tid & 3) * 16;
        const unsigned short* src = kvb + (size_t)(q0 + row) * N3_ + hq + cb;
        *reinterpret_cast<u16x8*>(&QP[row][cb])     = *reinterpret_cast<const u16x8*>(src);
        *reinterpret_cast<u16x8*>(&QP[row][cb + 8]) = *reinterpret_cast<const u16x8*>(src + 8);
    }

    // staging geometry (512 threads share one 64x64 K tile + V tile)
    const int krow = tid >> 3, kcb = (tid & 7) * 8;           // K: 1 x u16x8 each
    const int vkb = (tid & 31) * 2, vdb = (tid >> 5) * 4;     // V: 2 keys x 4 dims
    u16x8 kr;
    u16x4 vr0, vr1;

    // preload tile 0 and write to buf 0
    {
        kr  = *reinterpret_cast<const u16x8*>(kvb + (size_t)krow * N3_ + hk + kcb);
        const unsigned short* vs = kvb + (size_t)vkb * N3_ + hv + vdb;
        vr0 = *reinterpret_cast<const u16x4*>(vs);
        vr1 = *reinterpret_cast<const u16x4*>(vs + N3_);
        *reinterpret_cast<u16x8*>(&Kt[0][krow][kcb]) = kr;
#pragma unroll
        for (int j = 0; j < 4; ++j)
            *reinterpret_cast<u16x2*>(&Vt[0][vdb + j][vkb]) = (u16x2){vr0[j], vr1[j]};
    }
    __syncthreads();

    // Q fragments (registers; QP rows are reused as P strips afterwards)
    const short8 qa0 = *reinterpret_cast<const short8*>(&QP[wq*16 + l16][g*8]);
    const short8 qa1 = *reinterpret_cast<const short8*>(&QP[wq*16 + l16][32 + g*8]);

    f32x4 Oacc[4];
#pragma unroll
    for (int df = 0; df < 4; ++df) Oacc[df] = (f32x4){0.f, 0.f, 0.f, 0.f};
    float m = -1e30f, l = 0.0f;

    const float LOG2E = 1.4426950408889634f;
    const float c1 = 0.03125f * LOG2E;                       // scale * log2e
    const float c2 = exp2f(-0.5f * (float)(h + 1)) * LOG2E;  // slope * log2e
    const int   qw0 = q0 + wq * 16;                          // wave's q-strip base
    const int   qg  = qw0 + l16;                             // this lane's q row
    float albr[4];
#pragma unroll
    for (int r = 0; r < 4; ++r) albr[r] = c2 * (float)(g4 + r);
    const float c2_16 = c2 * 16.0f;

    for (int t = 0; t < NT_; ++t) {
        const int k0 = t * 64;
        const int cur = t & 1;

        // ---- (A) issue next tile's global loads (land during compute)
        if (t + 1 < NT_) {
            const int kn = k0 + 64;
            kr  = *reinterpret_cast<const u16x8*>(kvb + (size_t)(kn + krow) * N3_ + hk + kcb);
            const unsigned short* vs = kvb + (size_t)(kn + vkb) * N3_ + hv + vdb;
            vr0 = *reinterpret_cast<const u16x4*>(vs);
            vr1 = *reinterpret_cast<const u16x4*>(vs + N3_);
        }

        // ---- (B) mask bias for this tile (global, cache-hot broadcast)
        f32x4 amv[4];
#pragma unroll
        for (int jb = 0; jb < 4; ++jb)
            amv[jb] = *reinterpret_cast<const f32x4*>(&mbp[k0 + jb * 16 + g4]);

        // ---- (C) swapped QK^T: lane holds 16 scores for q=l16, key=jb*16+g4+r
        float p_[4][4];
        __builtin_amdgcn_s_setprio(1);
#pragma unroll
        for (int jb = 0; jb < 4; ++jb) {
            short8 kb0 = *reinterpret_cast<const short8*>(&Kt[cur][jb*16 + l16][g*8]);
            short8 kb1 = *reinterpret_cast<const short8*>(&Kt[cur][jb*16 + l16][32 + g*8]);
            f32x4 c = (f32x4){0.f, 0.f, 0.f, 0.f};
            c = __builtin_amdgcn_mfma_f32_16x16x32_bf16(kb0, qa0, c, 0, 0, 0);
            c = __builtin_amdgcn_mfma_f32_16x16x32_bf16(kb1, qa1, c, 0, 0, 0);
#pragma unroll
            for (int r = 0; r < 4; ++r) p_[jb][r] = c[r];
        }
        __builtin_amdgcn_s_setprio(0);

        // ---- (D) scores in log2 domain; alibi + mask folded into fma addend
        if (k0 + 64 <= qw0) {          // all keys < wave's q-strip
            const float tb = c2 * (float)(k0 - qg);
#pragma unroll
            for (int jb = 0; jb < 4; ++jb) {
                const float tbj = tb + c2_16 * (float)jb;
#pragma unroll
                for (int r = 0; r < 4; ++r)
                    p_[jb][r] = fmaf(p_[jb][r], c1, tbj + albr[r] + amv[jb][r]);
            }
        } else if (k0 >= qw0 + 16) {   // all keys > wave's q-strip
            const float tb = c2 * (float)(k0 - qg);
#pragma unroll
            for (int jb = 0; jb < 4; ++jb) {
                const float tbj = -tb - c2_16 * (float)jb;
#pragma unroll
                for (int r = 0; r < 4; ++r)
                    p_[jb][r] = fmaf(p_[jb][r], c1, tbj - albr[r] + amv[jb][r]);
            }
        } else {                       // mixed tile (exactly one per wave)
            const int dbase = k0 - qg;
#pragma unroll
            for (int jb = 0; jb < 4; ++jb)
#pragma unroll
                for (int r = 0; r < 4; ++r) {
                    int d = dbase + jb * 16 + g4 + r;
                    d = d < 0 ? -d : d;
                    p_[jb][r] = fmaf(p_[jb][r], c1, amv[jb][r] - c2 * (float)d);
                }
        }

        // ---- row max (masked scores are -1e30: excluded naturally)
        float mx;
        {
            float m0_ = fmaxf(fmaxf(p_[0][0], p_[0][1]), fmaxf(p_[0][2], p_[0][3]));
            float m1_ = fmaxf(fmaxf(p_[1][0], p_[1][1]), fmaxf(p_[1][2], p_[1][3]));
            float m2_ = fmaxf(fmaxf(p_[2][0], p_[2][1]), fmaxf(p_[2][2], p_[2][3]));
            float m3_ = fmaxf(fmaxf(p_[3][0], p_[3][1]), fmaxf(p_[3][2], p_[3][3]));
            mx = fmaxf(fmaxf(m0_, m1_), fmaxf(m2_, m3_));
        }
        mx = fmaxf(mx, __shfl_xor(mx, 16));
        mx = fmaxf(mx, __shfl_xor(mx, 32));

        // ---- defer-max rescale (rare)
        if (__any(mx > m + 8.0f)) {
            const float mn = fmaxf(m, mx);
            const float cr = exp2_(m - mn);
            m = mn;
            l *= cr;
            const int srcb = (lane & 48) + ((lane & 48) >> 2);
#pragma unroll
            for (int r = 0; r < 4; ++r) {
                const float crq = __shfl(cr, srcb + r);
#pragma unroll
                for (int df = 0; df < 4; ++df) Oacc[df][r] *= crq;
            }
        }

        // ---- (E) exp + local sum (masked -> exp2(-huge) = 0)
        float ps = 0.0f;
#pragma unroll
        for (int jb = 0; jb < 4; ++jb)
#pragma unroll
            for (int r = 0; r < 4; ++r) {
                float p = exp2_(p_[jb][r] - m);
                p_[jb][r] = p;
                ps += p;
            }

        // ---- (F) pack P, write to own wave's LDS strip (same-wave read)
#pragma unroll
        for (int jb = 0; jb < 4; ++jb) {
            uint2 st;
            st.x = cvt_pk_bf16(p_[jb][0], p_[jb][1]);
            st.y = cvt_pk_bf16(p_[jb][2], p_[jb][3]);
            *reinterpret_cast<uint2*>(&QP[wq*16 + l16][jb*16 + g4]) = st;
        }

        // ---- (G) PV: A = P, B = Vt
        const short8 pa0 = *reinterpret_cast<const short8*>(&QP[wq*16 + l16][g*8]);
        const short8 pa1 = *reinterpret_cast<const short8*>(&QP[wq*16 + l16][32 + g*8]);
        __builtin_amdgcn_s_setprio(1);
#pragma unroll
        for (int df = 0; df < 4; ++df) {
            short8 vb0 = *reinterpret_cast<const short8*>(&Vt[cur][df*16 + l16][g*8]);
            short8 vb1 = *reinterpret_cast<const short8*>(&Vt[cur][df*16 + l16][32 + g*8]);
            Oacc[df] = __builtin_amdgcn_mfma_f32_16x16x32_bf16(pa0, vb0, Oacc[df], 0, 0, 0);
            Oacc[df] = __builtin_amdgcn_mfma_f32_16x16x32_bf16(pa1, vb1, Oacc[df], 0, 0, 0);
        }
        __builtin_amdgcn_s_setprio(0);

        // ---- (H) deferred l update
        ps += __shfl_xor(ps, 16);
        ps += __shfl_xor(ps, 32);
        l += ps;

        // ---- (I) write staged regs -> other buffer, (J) single barrier
        if (t + 1 < NT_) {
            *reinterpret_cast<u16x8*>(&Kt[cur ^ 1][krow][kcb]) = kr;
#pragma unroll
            for (int j = 0; j < 4; ++j)
                *reinterpret_cast<u16x2*>(&Vt[cur ^ 1][vdb + j][vkb]) = (u16x2){vr0[j], vr1[j]};
            __syncthreads();
        }
    }

    // ---- normalize (l lives at lane l16=q; broadcast to output rows) + store
    const int srcb = (lane & 48) + ((lane & 48) >> 2);
    float invq[4];
#pragma unroll
    for (int r = 0; r < 4; ++r) invq[r] = 1.0f / __shfl(l, srcb + r);
#pragma unroll
    for (int df = 0; df < 4; ++df) {
#pragma unroll
        for (int r = 0; r < 4; ++r) {
            const int qrow = q0 + wq * 16 + g4 + r;
            x[(size_t)(b * S_ + qrow) * D_ + h * 64 + df * 16 + l16] = f2bf(Oacc[df][r] * invq[r]);
        }
    }
}

// ---------------------------------------------------------------------------
extern "C" void kernel_launch(void* const* d_in, const int* in_sizes, int n_in,
                              void* d_out, int out_size, void* d_ws, size_t ws_size,
                              hipStream_t stream) {
    const float* inputs = (const float*)d_in[0];
    const void*  mask   = d_in[1];
    const float* Wqkv   = (const float*)d_in[2];
    const float* bqkv   = (const float*)d_in[3];
    const float* Wproj  = (const float*)d_in[4];
    const float* bproj  = (const float*)d_in[5];
    float* out = (float*)d_out;

    // workspace layout
    unsigned short* qkvb = (unsigned short*)d_ws;         // M*N3 bf16
    unsigned short* xb   = qkvb + (size_t)M_ * N3_;       // M*D  bf16
    unsigned short* Ab   = xb + (size_t)M_ * D_;          // M*D  bf16 (inputs)
    unsigned short* Wqb  = Ab + (size_t)M_ * D_;          // N3*D bf16
    unsigned short* Wpb  = Wqb + (size_t)N3_ * D_;        // D*D  bf16
    float* maskbias = (float*)(Wpb + (size_t)D_ * D_);    // M floats
    int*   flag     = (int*)(maskbias + M_);

    k_detect_mask<<<1, 256, 0, stream>>>((const unsigned char*)mask, flag);
    k_expand_mask<<<(M_ + 255) / 256, 256, 0, stream>>>(mask, flag, maskbias, M_);

    k_f2bf<<<(M_ * D_ / 4 + 255) / 256, 256, 0, stream>>>(inputs, Ab, M_ * D_);
    k_f2bf<<<(N3_ * D_ / 4 + 255) / 256, 256, 0, stream>>>(Wqkv, Wqb, N3_ * D_);
    k_f2bf<<<(D_ * D_ / 4 + 255) / 256, 256, 0, stream>>>(Wproj, Wpb, D_ * D_);

    dim3 g1(N3_ / 128, M_ / 128);   // 24 x 32
    k_gemm_bf16_nt<true><<<g1, 256, 0, stream>>>(Ab, Wqb, bqkv, qkvb, M_, N3_, D_);

    k_attn_mfma<<<B_ * H_ * (S_ / 128), 512, 0, stream>>>(qkvb, maskbias, xb);

    dim3 g2(D_ / 128, M_ / 128);    // 8 x 32
    k_gemm_bf16_nt<false><<<g2, 256, 0, stream>>>(xb, Wpb, bproj, out, M_, D_, D_);
}